// Round 12
// baseline (417.724 us; speedup 1.0000x reference)
//
#include <hip/hip_runtime.h>
#include <math.h>

#define NEG_SLOPE 0.2f

typedef __attribute__((ext_vector_type(8))) short short8;
typedef __attribute__((ext_vector_type(4))) float f32x4;

__device__ inline unsigned short f2bf(float f){
  union { float f; unsigned u; } v; v.f = f;
  unsigned r = v.u + 0x7fffu + ((v.u >> 16) & 1u);
  return (unsigned short)(r >> 16);
}
__device__ inline float bf2f(unsigned u){
  union { unsigned u; float f; } v; v.u = u << 16; return v.f;
}

// ---------------- CSR build ----------------
__global__ __launch_bounds__(256) void k_deg_count(const int* __restrict__ dst, int E, int* __restrict__ deg){
  int i = blockIdx.x*256 + threadIdx.x;
  if (i < E) atomicAdd(&deg[dst[i]], 1);
}
__global__ __launch_bounds__(256) void k_scan_blk(const int* __restrict__ deg, int* __restrict__ rowptr,
                                                  int* __restrict__ bsum, int N){
  __shared__ int ws[4];
  int tid = threadIdx.x;
  int i = blockIdx.x*256 + tid;
  int v = (i < N) ? deg[i]+1 : 0;   // +1 self-loop
  int lane = tid & 63, w = tid >> 6;
  int s = v;
  #pragma unroll
  for (int off=1; off<64; off<<=1){
    int u = __shfl_up(s, off);
    if (lane >= off) s += u;
  }
  if (lane == 63) ws[w] = s;
  __syncthreads();
  int woff = 0;
  #pragma unroll
  for (int k=0;k<4;k++) if (k < w) woff += ws[k];
  int incl = s + woff;
  if (i < N) rowptr[i] = incl - v;
  if (tid == 255) bsum[blockIdx.x] = incl;
}
__global__ __launch_bounds__(256) void k_scan_top(int* __restrict__ bsum, int nb, int* __restrict__ rowptrN){
  __shared__ int buf[256];
  int tid = threadIdx.x;
  int v = (tid < nb) ? bsum[tid] : 0;
  buf[tid] = v;
  __syncthreads();
  for (int off=1; off<256; off<<=1){
    int add = (tid >= off) ? buf[tid-off] : 0;
    __syncthreads();
    buf[tid] += add;
    __syncthreads();
  }
  if (tid < nb) bsum[tid] = buf[tid] - v;
  if (tid == 0) rowptrN[0] = buf[255];
}
__global__ __launch_bounds__(256) void k_scan_fix(int* __restrict__ rowptr, const int* __restrict__ bsum,
                                                  int* __restrict__ pos, int* __restrict__ colidx, int N){
  int i = blockIdx.x*256 + threadIdx.x;
  if (i < N){
    int r = rowptr[i] + bsum[blockIdx.x];
    rowptr[i] = r;
    colidx[r] = i;
    pos[i] = r + 1;
  }
}
__global__ __launch_bounds__(256) void k_fill_edges(const int* __restrict__ src, const int* __restrict__ dst,
                                                    int E, int* __restrict__ pos, int* __restrict__ colidx){
  int i = blockIdx.x*256 + threadIdx.x;
  if (i < E){
    int d = dst[i];
    colidx[atomicAdd(&pos[d],1)] = src[i];
  }
}

// ---------------- all weight prep in one launch ----------------
__global__ __launch_bounds__(256) void k_prep(const float* __restrict__ Wp, const float* __restrict__ W0,
                                              const float* __restrict__ W1, const float* __restrict__ Wv,
                                              const float* __restrict__ as0, const float* __restrict__ ad0,
                                              unsigned short* __restrict__ WpT, unsigned short* __restrict__ W0T4,
                                              unsigned short* __restrict__ W1T, unsigned short* __restrict__ WvT,
                                              float* __restrict__ ahs, float* __restrict__ ahd){
  int idx = blockIdx.x*256 + threadIdx.x;
  if (idx < 16384){
    int k = idx >> 6, p = idx & 63;
    WpT[p*256 + k] = f2bf(Wp[idx]);
  } else if (idx < 32768){
    int i = idx - 16384;
    int h = i >> 12, r = i & 4095, p = r >> 6, k = r & 63;
    W0T4[i] = f2bf(W0[k*256 + h*64 + p]);
  } else if (idx < 98304){
    int i = idx - 32768; int k = i >> 8, p = i & 255;
    W1T[p*256 + k] = f2bf(W1[i]);
  } else if (idx < 163840){
    int i = idx - 98304; int k = i >> 8, p = i & 255;
    WvT[p*256 + k] = f2bf(Wv[i]);
  } else if (idx < 164096){
    int i = idx - 163840;
    int h = i >> 6, d = i & 63;
    float ss = 0.f, sd = 0.f;
    for (int j=0;j<64;j++){
      float w = W0[d*256 + h*64 + j];
      ss += w * as0[h*64 + j];
      sd += w * ad0[h*64 + j];
    }
    ahs[i] = ss; ahd[i] = sd;
  }
}

// ---------------- h0 = x @ Wp + bp : direct-fragment MFMA GEMM ----------------
__global__ __launch_bounds__(256) void k_h0(const float* __restrict__ A,
                                            const unsigned short* __restrict__ Bt,
                                            const float* __restrict__ bias,
                                            unsigned short* __restrict__ C, int M, int Nn){
  int wid = blockIdx.x*4 + (threadIdx.x >> 6);
  int m0 = wid * 64;
  if (m0 >= M) return;
  int lane = threadIdx.x & 63;
  int lr = lane & 15, g = lane >> 4, lk = g*8;
  const float* Arow[4];
  #pragma unroll
  for (int m=0;m<4;m++){
    int row = m0 + m*16 + lr;
    if (row > M-1) row = M-1;
    Arow[m] = A + (size_t)row*256 + lk;
  }
  const unsigned short* Bb = Bt + (size_t)lr*256 + lk;
  f32x4 acc[4][4];
  #pragma unroll
  for (int m=0;m<4;m++)
    #pragma unroll
    for (int n=0;n<4;n++)
      #pragma unroll
      for (int j=0;j<4;j++) acc[m][n][j] = 0.f;

  #pragma unroll 2
  for (int ks=0; ks<8; ks++){
    int k0 = ks*32;
    short8 bfr[4];
    #pragma unroll
    for (int n=0;n<4;n++)
      bfr[n] = *(const short8*)(Bb + (size_t)n*16*256 + k0);
    short8 afr[4];
    #pragma unroll
    for (int m=0;m<4;m++){
      float4 u = *(const float4*)(Arow[m] + k0);
      float4 w = *(const float4*)(Arow[m] + k0 + 4);
      afr[m][0]=(short)f2bf(u.x); afr[m][1]=(short)f2bf(u.y);
      afr[m][2]=(short)f2bf(u.z); afr[m][3]=(short)f2bf(u.w);
      afr[m][4]=(short)f2bf(w.x); afr[m][5]=(short)f2bf(w.y);
      afr[m][6]=(short)f2bf(w.z); afr[m][7]=(short)f2bf(w.w);
    }
    #pragma unroll
    for (int m=0;m<4;m++)
      #pragma unroll
      for (int n=0;n<4;n++)
        acc[m][n] = __builtin_amdgcn_mfma_f32_16x16x32_bf16(afr[m], bfr[n], acc[m][n], 0,0,0);
  }
  #pragma unroll
  for (int n=0;n<4;n++){
    int col = n*16 + lr;
    float bcol = bias[col];
    #pragma unroll
    for (int m=0;m<4;m++){
      #pragma unroll
      for (int j=0;j<4;j++){
        int row = m0 + m*16 + g*4 + j;
        if (row < M){
          int t = row & 3, nn = row >> 2;
          C[(size_t)t*Nn*64 + (size_t)nn*64 + col] = f2bf(acc[m][n][j] + bcol);
        }
      }
    }
  }
}

// ---------------- fused layer-0 GEMMs + layer-1 logits (BK=32 Bls, 3 blocks/CU) ----------------
// hp = ELU(agg0 @ blockdiag(W0) + b0) @ W1, then e_s/e_d from fp32 hp in-register.
__global__ __launch_bounds__(256) void k_gat01(const unsigned short* __restrict__ A,    // agg0 [M][256]
                                               const unsigned short* __restrict__ W0T4, // [4][64p][64k]
                                               const float* __restrict__ b0,
                                               const unsigned short* __restrict__ W1T,  // [256p][256k]
                                               const float* __restrict__ as1,           // flat [256]
                                               const float* __restrict__ ad1,           // flat [256]
                                               unsigned short* __restrict__ hp,
                                               float* __restrict__ e_s, float* __restrict__ e_d,
                                               int M){
  __shared__ unsigned short H1[64][260];
  __shared__ unsigned short Bls[256][36];
  int tid = threadIdx.x;
  int m0 = blockIdx.x * 64;
  int wave = tid >> 6, lane = tid & 63;
  int lr = lane & 15, g4 = lane >> 4, lk = g4*8;
  int rbase = m0 + wave*16;

  // phase 1: h1 tile (per-head K=64 GEMM, direct fragments) -> LDS
  f32x4 acc1[16];
  #pragma unroll
  for (int q=0;q<16;q++)
    #pragma unroll
    for (int j=0;j<4;j++) acc1[q][j] = 0.f;
  int arow = rbase + lr; if (arow > M-1) arow = M-1;
  #pragma unroll
  for (int h=0;h<4;h++){
    short8 afr[2];
    #pragma unroll
    for (int ks=0;ks<2;ks++)
      afr[ks] = *(const short8*)(A + (size_t)arow*256 + h*64 + ks*32 + lk);
    #pragma unroll
    for (int nn=0;nn<4;nn++){
      #pragma unroll
      for (int ks=0;ks<2;ks++){
        short8 bfr = *(const short8*)(W0T4 + ((size_t)h*64 + nn*16 + lr)*64 + ks*32 + lk);
        acc1[h*4+nn] = __builtin_amdgcn_mfma_f32_16x16x32_bf16(afr[ks], bfr, acc1[h*4+nn], 0,0,0);
      }
    }
  }
  #pragma unroll
  for (int q=0;q<16;q++){
    int col = q*16 + lr;
    float bcol = b0[col];
    #pragma unroll
    for (int j=0;j<4;j++){
      float v = acc1[q][j] + bcol;
      v = (v > 0.f) ? v : (__expf(v) - 1.f);
      H1[wave*16 + g4*4 + j][col] = f2bf(v);
    }
  }
  __syncthreads();

  // phase 2: hp tile = H1 @ W1 (K=256), W1 staged in BK=32 slices
  f32x4 acc2[16];
  #pragma unroll
  for (int q=0;q<16;q++)
    #pragma unroll
    for (int j=0;j<4;j++) acc2[q][j] = 0.f;
  for (int k0=0;k0<256;k0+=32){
    #pragma unroll
    for (int it=0; it<4; it++){
      int idx = tid + it*256;
      int p = idx >> 2, ch = (idx & 3)*8;
      *(uint4*)(&Bls[p][ch]) = *(const uint4*)(W1T + (size_t)p*256 + k0 + ch);
    }
    __syncthreads();
    short8 afr = *(const short8*)(&H1[wave*16 + lr][k0 + lk]);
    #pragma unroll
    for (int q=0;q<16;q++){
      short8 bfr = *(const short8*)(&Bls[q*16 + lr][lk]);
      acc2[q] = __builtin_amdgcn_mfma_f32_16x16x32_bf16(afr, bfr, acc2[q], 0,0,0);
    }
    __syncthreads();
  }
  #pragma unroll
  for (int q=0;q<16;q++){
    int col = q*16 + lr;
    #pragma unroll
    for (int j=0;j<4;j++){
      int row = m0 + wave*16 + g4*4 + j;
      if (row < M)
        hp[(size_t)row*256 + col] = f2bf(acc2[q][j]);
    }
  }

  // fused layer-1 logits from fp32 acc2 (wave owns full 256-wide rows)
  float esp0[4], esp1[4], esp2[4], esp3[4];
  float edp0[4], edp1[4], edp2[4], edp3[4];
  #pragma unroll
  for (int j=0;j<4;j++){ esp0[j]=0.f; esp1[j]=0.f; esp2[j]=0.f; esp3[j]=0.f;
                         edp0[j]=0.f; edp1[j]=0.f; edp2[j]=0.f; edp3[j]=0.f; }
  #pragma unroll
  for (int q=0;q<16;q++){
    int col = q*16 + lr;
    float asv = as1[col], adv = ad1[col];
    #pragma unroll
    for (int j=0;j<4;j++){
      float v = acc2[q][j];
      if ((q>>2)==0){ esp0[j] += v*asv; edp0[j] += v*adv; }
      if ((q>>2)==1){ esp1[j] += v*asv; edp1[j] += v*adv; }
      if ((q>>2)==2){ esp2[j] += v*asv; edp2[j] += v*adv; }
      if ((q>>2)==3){ esp3[j] += v*asv; edp3[j] += v*adv; }
    }
  }
  #pragma unroll
  for (int j=0;j<4;j++){
    #pragma unroll
    for (int off=1; off<16; off<<=1){
      esp0[j] += __shfl_xor(esp0[j], off); edp0[j] += __shfl_xor(edp0[j], off);
      esp1[j] += __shfl_xor(esp1[j], off); edp1[j] += __shfl_xor(edp1[j], off);
      esp2[j] += __shfl_xor(esp2[j], off); edp2[j] += __shfl_xor(edp2[j], off);
      esp3[j] += __shfl_xor(esp3[j], off); edp3[j] += __shfl_xor(edp3[j], off);
    }
  }
  if (lr < 4){
    #pragma unroll
    for (int j=0;j<4;j++){
      int row = m0 + wave*16 + g4*4 + j;
      if (row < M){
        float ev = (lr==0)?esp0[j]:((lr==1)?esp1[j]:((lr==2)?esp2[j]:esp3[j]));
        float dv = (lr==0)?edp0[j]:((lr==1)?edp1[j]:((lr==2)?edp2[j]:edp3[j]));
        e_s[(size_t)row*4 + lr] = ev;
        e_d[(size_t)row*4 + lr] = dv;
      }
    }
  }
}

// ---------------- final GEMM with fused temporal combine in A-staging ----------------
__global__ __launch_bounds__(512) void k_gemm_fin(const unsigned short* __restrict__ embs,
                                                  const float* __restrict__ awp,
                                                  const unsigned short* __restrict__ Bt,
                                                  const float* __restrict__ bias,
                                                  float* __restrict__ C, int M){
  constexpr int K = 256, BK = 64, PAD = 8;
  __shared__ unsigned short Als[128][BK+PAD];
  __shared__ unsigned short Bls[256][BK+PAD];
  int tid = threadIdx.x;
  int m0  = blockIdx.x * 128;
  int wave = tid >> 6, lane = tid & 63;
  int wr = wave & 3, wc = wave >> 2;
  int lr = lane & 15, lk = (lane >> 4) * 8;
  float a0=awp[0], a1=awp[1], a2=awp[2], a3=awp[3];
  size_t sl = (size_t)M*256;
  f32x4 acc[2][8];
  #pragma unroll
  for (int m=0;m<2;m++)
    #pragma unroll
    for (int n=0;n<8;n++)
      #pragma unroll
      for (int j=0;j<4;j++) acc[m][n][j] = 0.f;

  for (int k0 = 0; k0 < K; k0 += BK){
    #pragma unroll
    for (int i=0;i<2;i++){
      int idx = tid + i*512;
      int r = idx >> 3, ch = (idx & 7)*8;
      int row = m0 + r;
      uint4 w = make_uint4(0,0,0,0);
      if (row < M){
        size_t o = (size_t)row*256 + k0 + ch;
        uint4 u0 = *(const uint4*)(embs + o);
        uint4 u1 = *(const uint4*)(embs + o + sl);
        uint4 u2 = *(const uint4*)(embs + o + 2*sl);
        uint4 u3 = *(const uint4*)(embs + o + 3*sl);
        const unsigned* p0=&u0.x; const unsigned* p1=&u1.x;
        const unsigned* p2=&u2.x; const unsigned* p3=&u3.x;
        unsigned* pw=&w.x;
        #pragma unroll
        for (int q=0;q<4;q++){
          float lo = a0*bf2f(p0[q]&0xffffu) + a1*bf2f(p1[q]&0xffffu) + a2*bf2f(p2[q]&0xffffu) + a3*bf2f(p3[q]&0xffffu);
          float hi = a0*bf2f(p0[q]>>16)     + a1*bf2f(p1[q]>>16)     + a2*bf2f(p2[q]>>16)     + a3*bf2f(p3[q]>>16);
          pw[q] = (unsigned)f2bf(lo) | ((unsigned)f2bf(hi) << 16);
        }
      }
      *(uint4*)(&Als[r][ch]) = w;
    }
    #pragma unroll
    for (int i=0;i<4;i++){
      int idx = tid + i*512;
      int r = idx >> 3, ch = (idx & 7)*8;
      *(uint4*)(&Bls[r][ch]) = *(const uint4*)(Bt + (size_t)r*K + k0 + ch);
    }
    __syncthreads();
    #pragma unroll
    for (int ks=0; ks<2; ks++){
      short8 afr[2], bfr[8];
      #pragma unroll
      for (int m=0;m<2;m++)
        afr[m] = *(const short8*)(&Als[wr*32 + m*16 + lr][ks*32 + lk]);
      #pragma unroll
      for (int n=0;n<8;n++)
        bfr[n] = *(const short8*)(&Bls[wc*128 + n*16 + lr][ks*32 + lk]);
      #pragma unroll
      for (int m=0;m<2;m++)
        #pragma unroll
        for (int n=0;n<8;n++)
          acc[m][n] = __builtin_amdgcn_mfma_f32_16x16x32_bf16(afr[m], bfr[n], acc[m][n], 0,0,0);
    }
    __syncthreads();
  }
  #pragma unroll
  for (int m=0;m<2;m++){
    #pragma unroll
    for (int n=0;n<8;n++){
      int col = wc*128 + n*16 + lr;
      float bcol = bias[col];
      #pragma unroll
      for (int j=0;j<4;j++){
        int row = m0 + wr*32 + m*16 + (lane>>4)*4 + j;
        if (row < M)
          C[(size_t)row*256 + col] = acc[m][n][j] + bcol;
      }
    }
  }
}

// ---------------- layer-0 logits ----------------
__global__ __launch_bounds__(256) void k_esd0(const unsigned short* __restrict__ h0,
                                              const float* __restrict__ ahs, const float* __restrict__ ahd,
                                              float* __restrict__ e_s, float* __restrict__ e_d, int M){
  int n = blockIdx.x*4 + (threadIdx.x >> 6);
  if (n >= M) return;
  int lane = threadIdx.x & 63;
  int h = lane >> 4, l4 = (lane & 15)*4;
  uint2 v = *(const uint2*)(h0 + (size_t)n*64 + l4);
  float v0 = bf2f(v.x & 0xffffu), v1 = bf2f(v.x >> 16);
  float v2 = bf2f(v.y & 0xffffu), v3 = bf2f(v.y >> 16);
  float4 as = *(const float4*)(ahs + h*64 + l4);
  float4 ad = *(const float4*)(ahd + h*64 + l4);
  float ps = v0*as.x + v1*as.y + v2*as.z + v3*as.w;
  float pd = v0*ad.x + v1*ad.y + v2*ad.z + v3*ad.w;
  #pragma unroll
  for (int off=1; off<16; off<<=1){ ps += __shfl_xor(ps,off); pd += __shfl_xor(pd,off); }
  if ((lane & 15) == 0){
    e_s[n*4+h] = ps; e_d[n*4+h] = pd;
  }
}

// ---------------- layer-0 aggregation: 2 edges/wave, 2-deep pair unroll ----------------
__global__ __launch_bounds__(256) void k_agg0(const unsigned short* __restrict__ h0all,
                                              const float* __restrict__ e_s, const float* __restrict__ e_d,
                                              const int* __restrict__ rowptr, const int* __restrict__ colidx,
                                              unsigned short* __restrict__ agg, int N){
  int n = blockIdx.x*4 + (threadIdx.x >> 6);
  if (n >= N) return;
  int t = blockIdx.y;
  int g = t*N + n;
  int lane = threadIdx.x & 63;
  int half = lane >> 5, l = lane & 31;
  int h = l >> 3, di = (l & 7)*8;
  int s0 = rowptr[n], s1 = rowptr[n+1];
  float ed = e_d[(size_t)g*4 + h];
  const unsigned short* h0t = h0all + (size_t)t*N*64;
  const float* est = e_s + (size_t)t*N*4;
  float z = 0.f;
  float a[8] = {0,0,0,0,0,0,0,0};
  int i = s0;
  for (; i+4 <= s1; i += 4){
    int sA = colidx[i + half];
    int sB = colidx[i + 2 + half];
    uint4 vA = *(const uint4*)(h0t + (size_t)sA*64 + di);
    uint4 vB = *(const uint4*)(h0t + (size_t)sB*64 + di);
    float eA = est[sA*4 + h] + ed;
    float eB = est[sB*4 + h] + ed;
    eA = fmaxf(eA, NEG_SLOPE*eA); eB = fmaxf(eB, NEG_SLOPE*eB);
    float wA = __expf(eA), wB = __expf(eB);
    z += wA + wB;
    a[0] += wA*bf2f(vA.x&0xffffu) + wB*bf2f(vB.x&0xffffu);
    a[1] += wA*bf2f(vA.x>>16)     + wB*bf2f(vB.x>>16);
    a[2] += wA*bf2f(vA.y&0xffffu) + wB*bf2f(vB.y&0xffffu);
    a[3] += wA*bf2f(vA.y>>16)     + wB*bf2f(vB.y>>16);
    a[4] += wA*bf2f(vA.z&0xffffu) + wB*bf2f(vB.z&0xffffu);
    a[5] += wA*bf2f(vA.z>>16)     + wB*bf2f(vB.z>>16);
    a[6] += wA*bf2f(vA.w&0xffffu) + wB*bf2f(vB.w&0xffffu);
    a[7] += wA*bf2f(vA.w>>16)     + wB*bf2f(vB.w>>16);
  }
  for (; i+2 <= s1; i += 2){
    int s = colidx[i + half];
    uint4 v = *(const uint4*)(h0t + (size_t)s*64 + di);
    float e = est[s*4 + h] + ed;
    e = fmaxf(e, NEG_SLOPE*e);
    float w = __expf(e);
    z += w;
    a[0] += w*bf2f(v.x&0xffffu); a[1] += w*bf2f(v.x>>16);
    a[2] += w*bf2f(v.y&0xffffu); a[3] += w*bf2f(v.y>>16);
    a[4] += w*bf2f(v.z&0xffffu); a[5] += w*bf2f(v.z>>16);
    a[6] += w*bf2f(v.w&0xffffu); a[7] += w*bf2f(v.w>>16);
  }
  if (i < s1 && half == 0){
    int s = colidx[i];
    uint4 v = *(const uint4*)(h0t + (size_t)s*64 + di);
    float e = est[s*4 + h] + ed;
    e = fmaxf(e, NEG_SLOPE*e);
    float w = __expf(e);
    z += w;
    a[0] += w*bf2f(v.x&0xffffu); a[1] += w*bf2f(v.x>>16);
    a[2] += w*bf2f(v.y&0xffffu); a[3] += w*bf2f(v.y>>16);
    a[4] += w*bf2f(v.z&0xffffu); a[5] += w*bf2f(v.z>>16);
    a[6] += w*bf2f(v.w&0xffffu); a[7] += w*bf2f(v.w>>16);
  }
  z += __shfl_xor(z, 32);
  #pragma unroll
  for (int q=0;q<8;q++) a[q] += __shfl_xor(a[q], 32);
  if (half == 0){
    float inv = 1.f / (z + 1e-16f);
    uint4 r;
    r.x = (unsigned)f2bf(a[0]*inv) | ((unsigned)f2bf(a[1]*inv) << 16);
    r.y = (unsigned)f2bf(a[2]*inv) | ((unsigned)f2bf(a[3]*inv) << 16);
    r.z = (unsigned)f2bf(a[4]*inv) | ((unsigned)f2bf(a[5]*inv) << 16);
    r.w = (unsigned)f2bf(a[6]*inv) | ((unsigned)f2bf(a[7]*inv) << 16);
    *(uint4*)(agg + (size_t)g*256 + l*8) = r;
  }
}

// ---------------- layer-1 aggregation: 2 edges/wave, 2-deep pair unroll + bias + ELU ----------------
__global__ __launch_bounds__(256) void k_agg(const unsigned short* __restrict__ hpall,
                                             const float* __restrict__ e_s, const float* __restrict__ e_d,
                                             const int* __restrict__ rowptr, const int* __restrict__ colidx,
                                             const float* __restrict__ bias, unsigned short* __restrict__ outb,
                                             int N){
  int n = blockIdx.x*4 + (threadIdx.x >> 6);
  if (n >= N) return;
  int t = blockIdx.y;
  int g = t*N + n;
  int lane = threadIdx.x & 63;
  int half = lane >> 5, l = lane & 31;
  int h = l >> 3, d0 = l*8;
  int s0 = rowptr[n], s1 = rowptr[n+1];
  float ed = e_d[(size_t)g*4 + h];
  const unsigned short* hpt = hpall + (size_t)t*N*256;
  const float* est = e_s + (size_t)t*N*4;
  float z = 0.f;
  float a[8] = {0,0,0,0,0,0,0,0};
  int i = s0;
  for (; i+4 <= s1; i += 4){
    int sA = colidx[i + half];
    int sB = colidx[i + 2 + half];
    uint4 vA = *(const uint4*)(hpt + (size_t)sA*256 + d0);
    uint4 vB = *(const uint4*)(hpt + (size_t)sB*256 + d0);
    float eA = est[sA*4 + h] + ed;
    float eB = est[sB*4 + h] + ed;
    eA = fmaxf(eA, NEG_SLOPE*eA); eB = fmaxf(eB, NEG_SLOPE*eB);
    float wA = __expf(eA), wB = __expf(eB);
    z += wA + wB;
    a[0] += wA*bf2f(vA.x&0xffffu) + wB*bf2f(vB.x&0xffffu);
    a[1] += wA*bf2f(vA.x>>16)     + wB*bf2f(vB.x>>16);
    a[2] += wA*bf2f(vA.y&0xffffu) + wB*bf2f(vB.y&0xffffu);
    a[3] += wA*bf2f(vA.y>>16)     + wB*bf2f(vB.y>>16);
    a[4] += wA*bf2f(vA.z&0xffffu) + wB*bf2f(vB.z&0xffffu);
    a[5] += wA*bf2f(vA.z>>16)     + wB*bf2f(vB.z>>16);
    a[6] += wA*bf2f(vA.w&0xffffu) + wB*bf2f(vB.w&0xffffu);
    a[7] += wA*bf2f(vA.w>>16)     + wB*bf2f(vB.w>>16);
  }
  for (; i+2 <= s1; i += 2){
    int s = colidx[i + half];
    uint4 v = *(const uint4*)(hpt + (size_t)s*256 + d0);
    float e = est[s*4 + h] + ed;
    e = fmaxf(e, NEG_SLOPE*e);
    float w = __expf(e);
    z += w;
    a[0] += w*bf2f(v.x&0xffffu); a[1] += w*bf2f(v.x>>16);
    a[2] += w*bf2f(v.y&0xffffu); a[3] += w*bf2f(v.y>>16);
    a[4] += w*bf2f(v.z&0xffffu); a[5] += w*bf2f(v.z>>16);
    a[6] += w*bf2f(v.w&0xffffu); a[7] += w*bf2f(v.w>>16);
  }
  if (i < s1 && half == 0){
    int s = colidx[i];
    uint4 v = *(const uint4*)(hpt + (size_t)s*256 + d0);
    float e = est[s*4 + h] + ed;
    e = fmaxf(e, NEG_SLOPE*e);
    float w = __expf(e);
    z += w;
    a[0] += w*bf2f(v.x&0xffffu); a[1] += w*bf2f(v.x>>16);
    a[2] += w*bf2f(v.y&0xffffu); a[3] += w*bf2f(v.y>>16);
    a[4] += w*bf2f(v.z&0xffffu); a[5] += w*bf2f(v.z>>16);
    a[6] += w*bf2f(v.w&0xffffu); a[7] += w*bf2f(v.w>>16);
  }
  z += __shfl_xor(z, 32);
  #pragma unroll
  for (int q=0;q<8;q++) a[q] += __shfl_xor(a[q], 32);
  if (half == 0){
    float inv = 1.f / (z + 1e-16f);
    float4 bA = *(const float4*)(bias + d0);
    float4 bB = *(const float4*)(bias + d0 + 4);
    float o[8];
    o[0]=a[0]*inv+bA.x; o[1]=a[1]*inv+bA.y; o[2]=a[2]*inv+bA.z; o[3]=a[3]*inv+bA.w;
    o[4]=a[4]*inv+bB.x; o[5]=a[5]*inv+bB.y; o[6]=a[6]*inv+bB.z; o[7]=a[7]*inv+bB.w;
    #pragma unroll
    for (int q=0;q<8;q++) o[q] = (o[q] > 0.f) ? o[q] : (__expf(o[q]) - 1.f);
    uint4 r;
    r.x = (unsigned)f2bf(o[0]) | ((unsigned)f2bf(o[1]) << 16);
    r.y = (unsigned)f2bf(o[2]) | ((unsigned)f2bf(o[3]) << 16);
    r.z = (unsigned)f2bf(o[4]) | ((unsigned)f2bf(o[5]) << 16);
    r.w = (unsigned)f2bf(o[6]) | ((unsigned)f2bf(o[7]) << 16);
    *(uint4*)(outb + (size_t)g*256 + d0) = r;
  }
}

// ---------------- column sums, batched: 64 chunks per t ----------------
__global__ __launch_bounds__(256) void k_colsum(const unsigned short* __restrict__ emb, float* __restrict__ sums, int N){
  __shared__ float red[8][256];
  int tid = threadIdx.x;
  int t = blockIdx.x >> 6, chunk = blockIdx.x & 63;
  int rows_per = (N + 63) / 64;
  int r0 = chunk * rows_per;
  int r1 = min(N, r0 + rows_per);
  const unsigned short* base = emb + (size_t)t*N*256;
  int c0 = (tid & 31)*8, rg = tid >> 5;
  float s[8] = {0,0,0,0,0,0,0,0};
  for (int r = r0 + rg; r < r1; r += 8){
    uint4 v = *(const uint4*)(base + (size_t)r*256 + c0);
    s[0] += bf2f(v.x & 0xffffu); s[1] += bf2f(v.x >> 16);
    s[2] += bf2f(v.y & 0xffffu); s[3] += bf2f(v.y >> 16);
    s[4] += bf2f(v.z & 0xffffu); s[5] += bf2f(v.z >> 16);
    s[6] += bf2f(v.w & 0xffffu); s[7] += bf2f(v.w >> 16);
  }
  #pragma unroll
  for (int j=0;j<8;j++) red[rg][c0+j] = s[j];
  __syncthreads();
  float tot = 0.f;
  #pragma unroll
  for (int g=0;g<8;g++) tot += red[g][tid];
  atomicAdd(&sums[t*256 + tid], tot);
}

// ---------------- temporal attention weights (tiny) ----------------
__global__ __launch_bounds__(256) void k_attn(const float* __restrict__ sum_emb,
                                              const float* __restrict__ Wq, const float* __restrict__ bq,
                                              const float* __restrict__ Wk, const float* __restrict__ bk,
                                              float* __restrict__ aw, int N){
  __shared__ float mean_s[4][256];
  __shared__ float red[256];
  __shared__ float scores_s[4];
  int j = threadIdx.x;
  float invN = 1.0f/(float)N;
  #pragma unroll
  for (int t=0;t<4;t++) mean_s[t][j] = sum_emb[t*256+j]*invN;
  __syncthreads();
  float q3 = bq[j];
  float kt0=bk[j], kt1=bk[j], kt2=bk[j], kt3=bk[j];
  for (int m=0;m<256;m++){
    float wq = Wq[m*256+j];
    float wk = Wk[m*256+j];
    float m0 = mean_s[0][m], m1 = mean_s[1][m], m2 = mean_s[2][m], m3 = mean_s[3][m];
    q3  += m3*wq;
    kt0 += m0*wk; kt1 += m1*wk; kt2 += m2*wk; kt3 += m3*wk;
  }
  float kts0=kt0, kts1=kt1, kts2=kt2, kts3=kt3;
  #pragma unroll
  for (int t=0;t<4;t++){
    float ktv = (t==0)?kts0:((t==1)?kts1:((t==2)?kts2:kts3));
    red[j] = q3*ktv;
    __syncthreads();
    for (int off=128; off>0; off>>=1){
      if (j < off) red[j] += red[j+off];
      __syncthreads();
    }
    if (j==0) scores_s[t] = red[0]*(1.0f/16.0f);
    __syncthreads();
  }
  if (j==0){
    float mx = fmaxf(fmaxf(scores_s[0],scores_s[1]),fmaxf(scores_s[2],scores_s[3]));
    float w0 = __expf(scores_s[0]-mx), w1 = __expf(scores_s[1]-mx),
          w2 = __expf(scores_s[2]-mx), w3 = __expf(scores_s[3]-mx);
    float s = w0+w1+w2+w3;
    aw[0]=w0/s; aw[1]=w1/s; aw[2]=w2/s; aw[3]=w3/s;
  }
}

extern "C" void kernel_launch(void* const* d_in, const int* in_sizes, int n_in,
                              void* d_out, int out_size, void* d_ws, size_t ws_size,
                              hipStream_t stream){
  (void)n_in; (void)out_size; (void)ws_size;
  const float* x   = (const float*)d_in[0];
  const int*   ei  = (const int*)d_in[1];
  const float* Wp  = (const float*)d_in[2];
  const float* bp  = (const float*)d_in[3];
  const float* W0  = (const float*)d_in[4];
  const float* as0 = (const float*)d_in[5];
  const float* ad0 = (const float*)d_in[6];
  const float* b0  = (const float*)d_in[7];
  const float* W1  = (const float*)d_in[8];
  const float* as1 = (const float*)d_in[9];
  const float* ad1 = (const float*)d_in[10];
  const float* b1  = (const float*)d_in[11];
  const float* Wq  = (const float*)d_in[12];
  const float* bq  = (const float*)d_in[13];
  const float* Wk  = (const float*)d_in[14];
  const float* bk  = (const float*)d_in[15];
  const float* Wv  = (const float*)d_in[16];
  const float* bv  = (const float*)d_in[17];
  float* out = (float*)d_out;

  const int T = 4, FIN = 256;
  const int N = in_sizes[0] / (T*FIN);
  const int E = in_sizes[1] / 2;
  const int TN = T*N;
  const int* src = ei;
  const int* dst = ei + E;

  char* ws = (char*)d_ws;
  size_t cur = 0;
  auto alloc = [&](size_t bytes)->void*{
    void* p = ws + cur;
    cur += (bytes + 255) & ~(size_t)255;
    return p;
  };
  unsigned short* h0all = (unsigned short*)alloc((size_t)TN*64*2);
  unsigned short* bufA  = (unsigned short*)alloc((size_t)TN*256*2);   // agg0_all
  unsigned short* bufB  = (unsigned short*)alloc((size_t)TN*256*2);   // hp_all
  unsigned short* embs  = (unsigned short*)alloc((size_t)TN*256*2);
  float* e_s    = (float*)alloc((size_t)TN*4*4);
  float* e_d    = (float*)alloc((size_t)TN*4*4);
  float* sume   = (float*)alloc(4*256*4);
  float* aw     = (float*)alloc(256);
  float* ah0s   = (float*)alloc(256*4);
  float* ah0d   = (float*)alloc(256*4);
  int*   rowptr = (int*)alloc((size_t)(N+1)*4);
  int*   deg    = (int*)alloc((size_t)N*4);
  int*   pos    = (int*)alloc((size_t)N*4);
  int*   bsum   = (int*)alloc((size_t)256*4);
  int*   colidx = (int*)alloc((size_t)(E+N)*4);
  unsigned short* WpT  = (unsigned short*)alloc((size_t)64*256*2);
  unsigned short* W0T4 = (unsigned short*)alloc((size_t)4*64*64*2);
  unsigned short* W1T  = (unsigned short*)alloc((size_t)256*256*2);
  unsigned short* WvT  = (unsigned short*)alloc((size_t)256*256*2);

  int nb256 = (N+255)/256;
  int nbE   = (E+255)/256;
  int gmN   = (N+127)/128;
  int gagg  = (TN+3)/4;

  // CSR build (graph static across t and layers)
  hipMemsetAsync(deg, 0, (size_t)N*4, stream);
  k_deg_count<<<nbE,256,0,stream>>>(dst, E, deg);
  k_scan_blk<<<nb256,256,0,stream>>>(deg, rowptr, bsum, N);
  k_scan_top<<<1,256,0,stream>>>(bsum, nb256, rowptr + N);
  k_scan_fix<<<nb256,256,0,stream>>>(rowptr, bsum, pos, colidx, N);
  k_fill_edges<<<nbE,256,0,stream>>>(src, dst, E, pos, colidx);
  hipMemsetAsync(sume, 0, 4*256*4, stream);

  // weight prep
  k_prep<<<641,256,0,stream>>>(Wp, W0, W1, Wv, as0, ad0, WpT, W0T4, W1T, WvT, ah0s, ah0d);

  // h0 for all 4 timesteps
  k_h0<<<(TN/64+3)/4 + 1,256,0,stream>>>(x, WpT, bp, h0all, TN, N);

  // GAT layer 0 (batched over t): logits, gather-agg, fused W0+W1 GEMM (+layer-1 logits)
  k_esd0<<<gagg,256,0,stream>>>(h0all, ah0s, ah0d, e_s, e_d, TN);
  k_agg0<<<dim3((N+3)/4, T),256,0,stream>>>(h0all, e_s, e_d, rowptr, colidx, bufA, N);
  k_gat01<<<(TN+63)/64,256,0,stream>>>(bufA, W0T4, b0, W1T, as1, ad1, bufB, e_s, e_d, TN);
  // GAT layer 1 aggregation (e_s/e_d already produced by k_gat01)
  k_agg<<<dim3((N+3)/4, T),256,0,stream>>>(bufB, e_s, e_d, rowptr, colidx, b1, embs, N);
  // node-mean numerators for temporal attention
  k_colsum<<<256,256,0,stream>>>(embs, sume, N);

  // temporal attention weights, then final GEMM with fused combine
  k_attn<<<1,256,0,stream>>>(sume, Wq, bq, Wk, bk, aw, N);
  k_gemm_fin<<<gmN,512,0,stream>>>(embs, aw, WvT, bv, out, N);
}

// Round 13
// 402.146 us; speedup vs baseline: 1.0387x; 1.0387x over previous
//
#include <hip/hip_runtime.h>
#include <math.h>

#define NEG_SLOPE 0.2f

typedef __attribute__((ext_vector_type(8))) short short8;
typedef __attribute__((ext_vector_type(4))) float f32x4;

__device__ inline unsigned short f2bf(float f){
  union { float f; unsigned u; } v; v.f = f;
  unsigned r = v.u + 0x7fffu + ((v.u >> 16) & 1u);
  return (unsigned short)(r >> 16);
}
__device__ inline float bf2f(unsigned u){
  union { unsigned u; float f; } v; v.u = u << 16; return v.f;
}

// ---------------- CSR build ----------------
__global__ __launch_bounds__(256) void k_deg_count(const int* __restrict__ dst, int E, int* __restrict__ deg){
  int i = blockIdx.x*256 + threadIdx.x;
  if (i < E) atomicAdd(&deg[dst[i]], 1);
}
__global__ __launch_bounds__(256) void k_scan_blk(const int* __restrict__ deg, int* __restrict__ rowptr,
                                                  int* __restrict__ bsum, int N){
  __shared__ int ws[4];
  int tid = threadIdx.x;
  int i = blockIdx.x*256 + tid;
  int v = (i < N) ? deg[i]+1 : 0;   // +1 self-loop
  int lane = tid & 63, w = tid >> 6;
  int s = v;
  #pragma unroll
  for (int off=1; off<64; off<<=1){
    int u = __shfl_up(s, off);
    if (lane >= off) s += u;
  }
  if (lane == 63) ws[w] = s;
  __syncthreads();
  int woff = 0;
  #pragma unroll
  for (int k=0;k<4;k++) if (k < w) woff += ws[k];
  int incl = s + woff;
  if (i < N) rowptr[i] = incl - v;
  if (tid == 255) bsum[blockIdx.x] = incl;
}
__global__ __launch_bounds__(256) void k_scan_top(int* __restrict__ bsum, int nb, int* __restrict__ rowptrN){
  __shared__ int buf[256];
  int tid = threadIdx.x;
  int v = (tid < nb) ? bsum[tid] : 0;
  buf[tid] = v;
  __syncthreads();
  for (int off=1; off<256; off<<=1){
    int add = (tid >= off) ? buf[tid-off] : 0;
    __syncthreads();
    buf[tid] += add;
    __syncthreads();
  }
  if (tid < nb) bsum[tid] = buf[tid] - v;
  if (tid == 0) rowptrN[0] = buf[255];
}
__global__ __launch_bounds__(256) void k_scan_fix(int* __restrict__ rowptr, const int* __restrict__ bsum,
                                                  int* __restrict__ pos, int* __restrict__ colidx, int N){
  int i = blockIdx.x*256 + threadIdx.x;
  if (i < N){
    int r = rowptr[i] + bsum[blockIdx.x];
    rowptr[i] = r;
    colidx[r] = i;
    pos[i] = r + 1;
  }
}
__global__ __launch_bounds__(256) void k_fill_edges(const int* __restrict__ src, const int* __restrict__ dst,
                                                    int E, int* __restrict__ pos, int* __restrict__ colidx){
  int i = blockIdx.x*256 + threadIdx.x;
  if (i < E){
    int d = dst[i];
    colidx[atomicAdd(&pos[d],1)] = src[i];
  }
}

// ---------------- all weight prep + buffer zeroing in one launch (runs FIRST) ----------------
__global__ __launch_bounds__(256) void k_prep(const float* __restrict__ Wp, const float* __restrict__ W0,
                                              const float* __restrict__ W1, const float* __restrict__ Wv,
                                              const float* __restrict__ as0, const float* __restrict__ ad0,
                                              unsigned short* __restrict__ WpT, unsigned short* __restrict__ W0T4,
                                              unsigned short* __restrict__ W1T, unsigned short* __restrict__ WvT,
                                              float* __restrict__ ahs, float* __restrict__ ahd,
                                              int* __restrict__ deg, float* __restrict__ sume, int N){
  int idx = blockIdx.x*256 + threadIdx.x;
  if (idx < 16384){
    int k = idx >> 6, p = idx & 63;
    WpT[p*256 + k] = f2bf(Wp[idx]);
  } else if (idx < 32768){
    int i = idx - 16384;
    int h = i >> 12, r = i & 4095, p = r >> 6, k = r & 63;
    W0T4[i] = f2bf(W0[k*256 + h*64 + p]);
  } else if (idx < 98304){
    int i = idx - 32768; int k = i >> 8, p = i & 255;
    W1T[p*256 + k] = f2bf(W1[i]);
  } else if (idx < 163840){
    int i = idx - 98304; int k = i >> 8, p = i & 255;
    WvT[p*256 + k] = f2bf(Wv[i]);
  } else if (idx < 164096){
    int i = idx - 163840;
    int h = i >> 6, d = i & 63;
    float ss = 0.f, sd = 0.f;
    for (int j=0;j<64;j++){
      float w = W0[d*256 + h*64 + j];
      ss += w * as0[h*64 + j];
      sd += w * ad0[h*64 + j];
    }
    ahs[i] = ss; ahd[i] = sd;
  } else if (idx < 165120){
    sume[idx - 164096] = 0.f;
  } else if (idx < 165120 + N){
    deg[idx - 165120] = 0;
  }
}

// ---------------- h0 = x @ Wp + bp : direct-fragment MFMA GEMM ----------------
__global__ __launch_bounds__(256) void k_h0(const float* __restrict__ A,
                                            const unsigned short* __restrict__ Bt,
                                            const float* __restrict__ bias,
                                            unsigned short* __restrict__ C, int M, int Nn){
  int wid = blockIdx.x*4 + (threadIdx.x >> 6);
  int m0 = wid * 64;
  if (m0 >= M) return;
  int lane = threadIdx.x & 63;
  int lr = lane & 15, g = lane >> 4, lk = g*8;
  const float* Arow[4];
  #pragma unroll
  for (int m=0;m<4;m++){
    int row = m0 + m*16 + lr;
    if (row > M-1) row = M-1;
    Arow[m] = A + (size_t)row*256 + lk;
  }
  const unsigned short* Bb = Bt + (size_t)lr*256 + lk;
  f32x4 acc[4][4];
  #pragma unroll
  for (int m=0;m<4;m++)
    #pragma unroll
    for (int n=0;n<4;n++)
      #pragma unroll
      for (int j=0;j<4;j++) acc[m][n][j] = 0.f;

  #pragma unroll 2
  for (int ks=0; ks<8; ks++){
    int k0 = ks*32;
    short8 bfr[4];
    #pragma unroll
    for (int n=0;n<4;n++)
      bfr[n] = *(const short8*)(Bb + (size_t)n*16*256 + k0);
    short8 afr[4];
    #pragma unroll
    for (int m=0;m<4;m++){
      float4 u = *(const float4*)(Arow[m] + k0);
      float4 w = *(const float4*)(Arow[m] + k0 + 4);
      afr[m][0]=(short)f2bf(u.x); afr[m][1]=(short)f2bf(u.y);
      afr[m][2]=(short)f2bf(u.z); afr[m][3]=(short)f2bf(u.w);
      afr[m][4]=(short)f2bf(w.x); afr[m][5]=(short)f2bf(w.y);
      afr[m][6]=(short)f2bf(w.z); afr[m][7]=(short)f2bf(w.w);
    }
    #pragma unroll
    for (int m=0;m<4;m++)
      #pragma unroll
      for (int n=0;n<4;n++)
        acc[m][n] = __builtin_amdgcn_mfma_f32_16x16x32_bf16(afr[m], bfr[n], acc[m][n], 0,0,0);
  }
  #pragma unroll
  for (int n=0;n<4;n++){
    int col = n*16 + lr;
    float bcol = bias[col];
    #pragma unroll
    for (int m=0;m<4;m++){
      #pragma unroll
      for (int j=0;j<4;j++){
        int row = m0 + m*16 + g*4 + j;
        if (row < M){
          int t = row & 3, nn = row >> 2;
          C[(size_t)t*Nn*64 + (size_t)nn*64 + col] = f2bf(acc[m][n][j] + bcol);
        }
      }
    }
  }
}

// ---------------- fused layer-0 GEMMs + layer-1 logits (r11 config: BK=64) ----------------
__global__ __launch_bounds__(256) void k_gat01(const unsigned short* __restrict__ A,    // agg0 [M][256]
                                               const unsigned short* __restrict__ W0T4, // [4][64p][64k]
                                               const float* __restrict__ b0,
                                               const unsigned short* __restrict__ W1T,  // [256p][256k]
                                               const float* __restrict__ as1,           // flat [256]
                                               const float* __restrict__ ad1,           // flat [256]
                                               unsigned short* __restrict__ hp,
                                               float* __restrict__ e_s, float* __restrict__ e_d,
                                               int M){
  __shared__ unsigned short H1[64][264];
  __shared__ unsigned short Bls[256][72];
  int tid = threadIdx.x;
  int m0 = blockIdx.x * 64;
  int wave = tid >> 6, lane = tid & 63;
  int lr = lane & 15, g4 = lane >> 4, lk = g4*8;
  int rbase = m0 + wave*16;

  // phase 1: h1 tile (per-head K=64 GEMM, direct fragments) -> LDS
  f32x4 acc1[16];
  #pragma unroll
  for (int q=0;q<16;q++)
    #pragma unroll
    for (int j=0;j<4;j++) acc1[q][j] = 0.f;
  int arow = rbase + lr; if (arow > M-1) arow = M-1;
  #pragma unroll
  for (int h=0;h<4;h++){
    short8 afr[2];
    #pragma unroll
    for (int ks=0;ks<2;ks++)
      afr[ks] = *(const short8*)(A + (size_t)arow*256 + h*64 + ks*32 + lk);
    #pragma unroll
    for (int nn=0;nn<4;nn++){
      #pragma unroll
      for (int ks=0;ks<2;ks++){
        short8 bfr = *(const short8*)(W0T4 + ((size_t)h*64 + nn*16 + lr)*64 + ks*32 + lk);
        acc1[h*4+nn] = __builtin_amdgcn_mfma_f32_16x16x32_bf16(afr[ks], bfr, acc1[h*4+nn], 0,0,0);
      }
    }
  }
  #pragma unroll
  for (int q=0;q<16;q++){
    int col = q*16 + lr;
    float bcol = b0[col];
    #pragma unroll
    for (int j=0;j<4;j++){
      float v = acc1[q][j] + bcol;
      v = (v > 0.f) ? v : (__expf(v) - 1.f);
      H1[wave*16 + g4*4 + j][col] = f2bf(v);
    }
  }
  __syncthreads();

  // phase 2: hp tile = H1 @ W1 (K=256), W1 slice staged per step
  f32x4 acc2[16];
  #pragma unroll
  for (int q=0;q<16;q++)
    #pragma unroll
    for (int j=0;j<4;j++) acc2[q][j] = 0.f;
  for (int k0=0;k0<256;k0+=64){
    #pragma unroll
    for (int it=0; it<8; it++){
      int idx = tid + it*256;
      int p = idx >> 3, ch = (idx & 7)*8;
      *(uint4*)(&Bls[p][ch]) = *(const uint4*)(W1T + (size_t)p*256 + k0 + ch);
    }
    __syncthreads();
    #pragma unroll
    for (int ks=0;ks<2;ks++){
      short8 afr = *(const short8*)(&H1[wave*16 + lr][k0 + ks*32 + lk]);
      #pragma unroll
      for (int q=0;q<16;q++){
        short8 bfr = *(const short8*)(&Bls[q*16 + lr][ks*32 + lk]);
        acc2[q] = __builtin_amdgcn_mfma_f32_16x16x32_bf16(afr, bfr, acc2[q], 0,0,0);
      }
    }
    __syncthreads();
  }
  #pragma unroll
  for (int q=0;q<16;q++){
    int col = q*16 + lr;
    #pragma unroll
    for (int j=0;j<4;j++){
      int row = m0 + wave*16 + g4*4 + j;
      if (row < M)
        hp[(size_t)row*256 + col] = f2bf(acc2[q][j]);
    }
  }

  // fused layer-1 logits from fp32 acc2 (wave owns full 256-wide rows)
  float esp0[4], esp1[4], esp2[4], esp3[4];
  float edp0[4], edp1[4], edp2[4], edp3[4];
  #pragma unroll
  for (int j=0;j<4;j++){ esp0[j]=0.f; esp1[j]=0.f; esp2[j]=0.f; esp3[j]=0.f;
                         edp0[j]=0.f; edp1[j]=0.f; edp2[j]=0.f; edp3[j]=0.f; }
  #pragma unroll
  for (int q=0;q<16;q++){
    int col = q*16 + lr;
    float asv = as1[col], adv = ad1[col];
    #pragma unroll
    for (int j=0;j<4;j++){
      float v = acc2[q][j];
      if ((q>>2)==0){ esp0[j] += v*asv; edp0[j] += v*adv; }
      if ((q>>2)==1){ esp1[j] += v*asv; edp1[j] += v*adv; }
      if ((q>>2)==2){ esp2[j] += v*asv; edp2[j] += v*adv; }
      if ((q>>2)==3){ esp3[j] += v*asv; edp3[j] += v*adv; }
    }
  }
  #pragma unroll
  for (int j=0;j<4;j++){
    #pragma unroll
    for (int off=1; off<16; off<<=1){
      esp0[j] += __shfl_xor(esp0[j], off); edp0[j] += __shfl_xor(edp0[j], off);
      esp1[j] += __shfl_xor(esp1[j], off); edp1[j] += __shfl_xor(edp1[j], off);
      esp2[j] += __shfl_xor(esp2[j], off); edp2[j] += __shfl_xor(edp2[j], off);
      esp3[j] += __shfl_xor(esp3[j], off); edp3[j] += __shfl_xor(edp3[j], off);
    }
  }
  if (lr < 4){
    #pragma unroll
    for (int j=0;j<4;j++){
      int row = m0 + wave*16 + g4*4 + j;
      if (row < M){
        float ev = (lr==0)?esp0[j]:((lr==1)?esp1[j]:((lr==2)?esp2[j]:esp3[j]));
        float dv = (lr==0)?edp0[j]:((lr==1)?edp1[j]:((lr==2)?edp2[j]:edp3[j]));
        e_s[(size_t)row*4 + lr] = ev;
        e_d[(size_t)row*4 + lr] = dv;
      }
    }
  }
}

// ---------------- final GEMM with fused temporal combine in A-staging ----------------
__global__ __launch_bounds__(512) void k_gemm_fin(const unsigned short* __restrict__ embs,
                                                  const float* __restrict__ awp,
                                                  const unsigned short* __restrict__ Bt,
                                                  const float* __restrict__ bias,
                                                  float* __restrict__ C, int M){
  constexpr int K = 256, BK = 64, PAD = 8;
  __shared__ unsigned short Als[128][BK+PAD];
  __shared__ unsigned short Bls[256][BK+PAD];
  int tid = threadIdx.x;
  int m0  = blockIdx.x * 128;
  int wave = tid >> 6, lane = tid & 63;
  int wr = wave & 3, wc = wave >> 2;
  int lr = lane & 15, lk = (lane >> 4) * 8;
  float a0=awp[0], a1=awp[1], a2=awp[2], a3=awp[3];
  size_t sl = (size_t)M*256;
  f32x4 acc[2][8];
  #pragma unroll
  for (int m=0;m<2;m++)
    #pragma unroll
    for (int n=0;n<8;n++)
      #pragma unroll
      for (int j=0;j<4;j++) acc[m][n][j] = 0.f;

  for (int k0 = 0; k0 < K; k0 += BK){
    #pragma unroll
    for (int i=0;i<2;i++){
      int idx = tid + i*512;
      int r = idx >> 3, ch = (idx & 7)*8;
      int row = m0 + r;
      uint4 w = make_uint4(0,0,0,0);
      if (row < M){
        size_t o = (size_t)row*256 + k0 + ch;
        uint4 u0 = *(const uint4*)(embs + o);
        uint4 u1 = *(const uint4*)(embs + o + sl);
        uint4 u2 = *(const uint4*)(embs + o + 2*sl);
        uint4 u3 = *(const uint4*)(embs + o + 3*sl);
        const unsigned* p0=&u0.x; const unsigned* p1=&u1.x;
        const unsigned* p2=&u2.x; const unsigned* p3=&u3.x;
        unsigned* pw=&w.x;
        #pragma unroll
        for (int q=0;q<4;q++){
          float lo = a0*bf2f(p0[q]&0xffffu) + a1*bf2f(p1[q]&0xffffu) + a2*bf2f(p2[q]&0xffffu) + a3*bf2f(p3[q]&0xffffu);
          float hi = a0*bf2f(p0[q]>>16)     + a1*bf2f(p1[q]>>16)     + a2*bf2f(p2[q]>>16)     + a3*bf2f(p3[q]>>16);
          pw[q] = (unsigned)f2bf(lo) | ((unsigned)f2bf(hi) << 16);
        }
      }
      *(uint4*)(&Als[r][ch]) = w;
    }
    #pragma unroll
    for (int i=0;i<4;i++){
      int idx = tid + i*512;
      int r = idx >> 3, ch = (idx & 7)*8;
      *(uint4*)(&Bls[r][ch]) = *(const uint4*)(Bt + (size_t)r*K + k0 + ch);
    }
    __syncthreads();
    #pragma unroll
    for (int ks=0; ks<2; ks++){
      short8 afr[2], bfr[8];
      #pragma unroll
      for (int m=0;m<2;m++)
        afr[m] = *(const short8*)(&Als[wr*32 + m*16 + lr][ks*32 + lk]);
      #pragma unroll
      for (int n=0;n<8;n++)
        bfr[n] = *(const short8*)(&Bls[wc*128 + n*16 + lr][ks*32 + lk]);
      #pragma unroll
      for (int m=0;m<2;m++)
        #pragma unroll
        for (int n=0;n<8;n++)
          acc[m][n] = __builtin_amdgcn_mfma_f32_16x16x32_bf16(afr[m], bfr[n], acc[m][n], 0,0,0);
    }
    __syncthreads();
  }
  #pragma unroll
  for (int m=0;m<2;m++){
    #pragma unroll
    for (int n=0;n<8;n++){
      int col = wc*128 + n*16 + lr;
      float bcol = bias[col];
      #pragma unroll
      for (int j=0;j<4;j++){
        int row = m0 + wr*32 + m*16 + (lane>>4)*4 + j;
        if (row < M)
          C[(size_t)row*256 + col] = acc[m][n][j] + bcol;
      }
    }
  }
}

// ---------------- layer-0 logits ----------------
__global__ __launch_bounds__(256) void k_esd0(const unsigned short* __restrict__ h0,
                                              const float* __restrict__ ahs, const float* __restrict__ ahd,
                                              float* __restrict__ e_s, float* __restrict__ e_d, int M){
  int n = blockIdx.x*4 + (threadIdx.x >> 6);
  if (n >= M) return;
  int lane = threadIdx.x & 63;
  int h = lane >> 4, l4 = (lane & 15)*4;
  uint2 v = *(const uint2*)(h0 + (size_t)n*64 + l4);
  float v0 = bf2f(v.x & 0xffffu), v1 = bf2f(v.x >> 16);
  float v2 = bf2f(v.y & 0xffffu), v3 = bf2f(v.y >> 16);
  float4 as = *(const float4*)(ahs + h*64 + l4);
  float4 ad = *(const float4*)(ahd + h*64 + l4);
  float ps = v0*as.x + v1*as.y + v2*as.z + v3*as.w;
  float pd = v0*ad.x + v1*ad.y + v2*ad.z + v3*ad.w;
  #pragma unroll
  for (int off=1; off<16; off<<=1){ ps += __shfl_xor(ps,off); pd += __shfl_xor(pd,off); }
  if ((lane & 15) == 0){
    e_s[n*4+h] = ps; e_d[n*4+h] = pd;
  }
}

// ---------------- layer-0 aggregation: 2 edges/wave, 3-deep pair unroll (6 rows in flight) ----------------
__global__ __launch_bounds__(256) void k_agg0(const unsigned short* __restrict__ h0all,
                                              const float* __restrict__ e_s, const float* __restrict__ e_d,
                                              const int* __restrict__ rowptr, const int* __restrict__ colidx,
                                              unsigned short* __restrict__ agg, int N){
  int n = blockIdx.x*4 + (threadIdx.x >> 6);
  if (n >= N) return;
  int t = blockIdx.y;
  int g = t*N + n;
  int lane = threadIdx.x & 63;
  int half = lane >> 5, l = lane & 31;
  int h = l >> 3, di = (l & 7)*8;
  int s0 = rowptr[n], s1 = rowptr[n+1];
  float ed = e_d[(size_t)g*4 + h];
  const unsigned short* h0t = h0all + (size_t)t*N*64;
  const float* est = e_s + (size_t)t*N*4;
  float z = 0.f;
  float a[8] = {0,0,0,0,0,0,0,0};
  int i = s0;
  for (; i+6 <= s1; i += 6){
    int sA = colidx[i + half];
    int sB = colidx[i + 2 + half];
    int sC = colidx[i + 4 + half];
    uint4 vA = *(const uint4*)(h0t + (size_t)sA*64 + di);
    uint4 vB = *(const uint4*)(h0t + (size_t)sB*64 + di);
    uint4 vC = *(const uint4*)(h0t + (size_t)sC*64 + di);
    float eA = est[sA*4 + h] + ed;
    float eB = est[sB*4 + h] + ed;
    float eC = est[sC*4 + h] + ed;
    eA = fmaxf(eA, NEG_SLOPE*eA); eB = fmaxf(eB, NEG_SLOPE*eB); eC = fmaxf(eC, NEG_SLOPE*eC);
    float wA = __expf(eA), wB = __expf(eB), wC = __expf(eC);
    z += wA + wB + wC;
    a[0] += wA*bf2f(vA.x&0xffffu) + wB*bf2f(vB.x&0xffffu) + wC*bf2f(vC.x&0xffffu);
    a[1] += wA*bf2f(vA.x>>16)     + wB*bf2f(vB.x>>16)     + wC*bf2f(vC.x>>16);
    a[2] += wA*bf2f(vA.y&0xffffu) + wB*bf2f(vB.y&0xffffu) + wC*bf2f(vC.y&0xffffu);
    a[3] += wA*bf2f(vA.y>>16)     + wB*bf2f(vB.y>>16)     + wC*bf2f(vC.y>>16);
    a[4] += wA*bf2f(vA.z&0xffffu) + wB*bf2f(vB.z&0xffffu) + wC*bf2f(vC.z&0xffffu);
    a[5] += wA*bf2f(vA.z>>16)     + wB*bf2f(vB.z>>16)     + wC*bf2f(vC.z>>16);
    a[6] += wA*bf2f(vA.w&0xffffu) + wB*bf2f(vB.w&0xffffu) + wC*bf2f(vC.w&0xffffu);
    a[7] += wA*bf2f(vA.w>>16)     + wB*bf2f(vB.w>>16)     + wC*bf2f(vC.w>>16);
  }
  for (; i+2 <= s1; i += 2){
    int s = colidx[i + half];
    uint4 v = *(const uint4*)(h0t + (size_t)s*64 + di);
    float e = est[s*4 + h] + ed;
    e = fmaxf(e, NEG_SLOPE*e);
    float w = __expf(e);
    z += w;
    a[0] += w*bf2f(v.x&0xffffu); a[1] += w*bf2f(v.x>>16);
    a[2] += w*bf2f(v.y&0xffffu); a[3] += w*bf2f(v.y>>16);
    a[4] += w*bf2f(v.z&0xffffu); a[5] += w*bf2f(v.z>>16);
    a[6] += w*bf2f(v.w&0xffffu); a[7] += w*bf2f(v.w>>16);
  }
  if (i < s1 && half == 0){
    int s = colidx[i];
    uint4 v = *(const uint4*)(h0t + (size_t)s*64 + di);
    float e = est[s*4 + h] + ed;
    e = fmaxf(e, NEG_SLOPE*e);
    float w = __expf(e);
    z += w;
    a[0] += w*bf2f(v.x&0xffffu); a[1] += w*bf2f(v.x>>16);
    a[2] += w*bf2f(v.y&0xffffu); a[3] += w*bf2f(v.y>>16);
    a[4] += w*bf2f(v.z&0xffffu); a[5] += w*bf2f(v.z>>16);
    a[6] += w*bf2f(v.w&0xffffu); a[7] += w*bf2f(v.w>>16);
  }
  z += __shfl_xor(z, 32);
  #pragma unroll
  for (int q=0;q<8;q++) a[q] += __shfl_xor(a[q], 32);
  if (half == 0){
    float inv = 1.f / (z + 1e-16f);
    uint4 r;
    r.x = (unsigned)f2bf(a[0]*inv) | ((unsigned)f2bf(a[1]*inv) << 16);
    r.y = (unsigned)f2bf(a[2]*inv) | ((unsigned)f2bf(a[3]*inv) << 16);
    r.z = (unsigned)f2bf(a[4]*inv) | ((unsigned)f2bf(a[5]*inv) << 16);
    r.w = (unsigned)f2bf(a[6]*inv) | ((unsigned)f2bf(a[7]*inv) << 16);
    *(uint4*)(agg + (size_t)g*256 + l*8) = r;
  }
}

// ---------------- layer-1 aggregation: 2 edges/wave, 3-deep pair unroll + bias + ELU ----------------
__global__ __launch_bounds__(256) void k_agg(const unsigned short* __restrict__ hpall,
                                             const float* __restrict__ e_s, const float* __restrict__ e_d,
                                             const int* __restrict__ rowptr, const int* __restrict__ colidx,
                                             const float* __restrict__ bias, unsigned short* __restrict__ outb,
                                             int N){
  int n = blockIdx.x*4 + (threadIdx.x >> 6);
  if (n >= N) return;
  int t = blockIdx.y;
  int g = t*N + n;
  int lane = threadIdx.x & 63;
  int half = lane >> 5, l = lane & 31;
  int h = l >> 3, d0 = l*8;
  int s0 = rowptr[n], s1 = rowptr[n+1];
  float ed = e_d[(size_t)g*4 + h];
  const unsigned short* hpt = hpall + (size_t)t*N*256;
  const float* est = e_s + (size_t)t*N*4;
  float z = 0.f;
  float a[8] = {0,0,0,0,0,0,0,0};
  int i = s0;
  for (; i+6 <= s1; i += 6){
    int sA = colidx[i + half];
    int sB = colidx[i + 2 + half];
    int sC = colidx[i + 4 + half];
    uint4 vA = *(const uint4*)(hpt + (size_t)sA*256 + d0);
    uint4 vB = *(const uint4*)(hpt + (size_t)sB*256 + d0);
    uint4 vC = *(const uint4*)(hpt + (size_t)sC*256 + d0);
    float eA = est[sA*4 + h] + ed;
    float eB = est[sB*4 + h] + ed;
    float eC = est[sC*4 + h] + ed;
    eA = fmaxf(eA, NEG_SLOPE*eA); eB = fmaxf(eB, NEG_SLOPE*eB); eC = fmaxf(eC, NEG_SLOPE*eC);
    float wA = __expf(eA), wB = __expf(eB), wC = __expf(eC);
    z += wA + wB + wC;
    a[0] += wA*bf2f(vA.x&0xffffu) + wB*bf2f(vB.x&0xffffu) + wC*bf2f(vC.x&0xffffu);
    a[1] += wA*bf2f(vA.x>>16)     + wB*bf2f(vB.x>>16)     + wC*bf2f(vC.x>>16);
    a[2] += wA*bf2f(vA.y&0xffffu) + wB*bf2f(vB.y&0xffffu) + wC*bf2f(vC.y&0xffffu);
    a[3] += wA*bf2f(vA.y>>16)     + wB*bf2f(vB.y>>16)     + wC*bf2f(vC.y>>16);
    a[4] += wA*bf2f(vA.z&0xffffu) + wB*bf2f(vB.z&0xffffu) + wC*bf2f(vC.z&0xffffu);
    a[5] += wA*bf2f(vA.z>>16)     + wB*bf2f(vB.z>>16)     + wC*bf2f(vC.z>>16);
    a[6] += wA*bf2f(vA.w&0xffffu) + wB*bf2f(vB.w&0xffffu) + wC*bf2f(vC.w&0xffffu);
    a[7] += wA*bf2f(vA.w>>16)     + wB*bf2f(vB.w>>16)     + wC*bf2f(vC.w>>16);
  }
  for (; i+2 <= s1; i += 2){
    int s = colidx[i + half];
    uint4 v = *(const uint4*)(hpt + (size_t)s*256 + d0);
    float e = est[s*4 + h] + ed;
    e = fmaxf(e, NEG_SLOPE*e);
    float w = __expf(e);
    z += w;
    a[0] += w*bf2f(v.x&0xffffu); a[1] += w*bf2f(v.x>>16);
    a[2] += w*bf2f(v.y&0xffffu); a[3] += w*bf2f(v.y>>16);
    a[4] += w*bf2f(v.z&0xffffu); a[5] += w*bf2f(v.z>>16);
    a[6] += w*bf2f(v.w&0xffffu); a[7] += w*bf2f(v.w>>16);
  }
  if (i < s1 && half == 0){
    int s = colidx[i];
    uint4 v = *(const uint4*)(hpt + (size_t)s*256 + d0);
    float e = est[s*4 + h] + ed;
    e = fmaxf(e, NEG_SLOPE*e);
    float w = __expf(e);
    z += w;
    a[0] += w*bf2f(v.x&0xffffu); a[1] += w*bf2f(v.x>>16);
    a[2] += w*bf2f(v.y&0xffffu); a[3] += w*bf2f(v.y>>16);
    a[4] += w*bf2f(v.z&0xffffu); a[5] += w*bf2f(v.z>>16);
    a[6] += w*bf2f(v.w&0xffffu); a[7] += w*bf2f(v.w>>16);
  }
  z += __shfl_xor(z, 32);
  #pragma unroll
  for (int q=0;q<8;q++) a[q] += __shfl_xor(a[q], 32);
  if (half == 0){
    float inv = 1.f / (z + 1e-16f);
    float4 bA = *(const float4*)(bias + d0);
    float4 bB = *(const float4*)(bias + d0 + 4);
    float o[8];
    o[0]=a[0]*inv+bA.x; o[1]=a[1]*inv+bA.y; o[2]=a[2]*inv+bA.z; o[3]=a[3]*inv+bA.w;
    o[4]=a[4]*inv+bB.x; o[5]=a[5]*inv+bB.y; o[6]=a[6]*inv+bB.z; o[7]=a[7]*inv+bB.w;
    #pragma unroll
    for (int q=0;q<8;q++) o[q] = (o[q] > 0.f) ? o[q] : (__expf(o[q]) - 1.f);
    uint4 r;
    r.x = (unsigned)f2bf(o[0]) | ((unsigned)f2bf(o[1]) << 16);
    r.y = (unsigned)f2bf(o[2]) | ((unsigned)f2bf(o[3]) << 16);
    r.z = (unsigned)f2bf(o[4]) | ((unsigned)f2bf(o[5]) << 16);
    r.w = (unsigned)f2bf(o[6]) | ((unsigned)f2bf(o[7]) << 16);
    *(uint4*)(outb + (size_t)g*256 + d0) = r;
  }
}

// ---------------- column sums, batched: 64 chunks per t ----------------
__global__ __launch_bounds__(256) void k_colsum(const unsigned short* __restrict__ emb, float* __restrict__ sums, int N){
  __shared__ float red[8][256];
  int tid = threadIdx.x;
  int t = blockIdx.x >> 6, chunk = blockIdx.x & 63;
  int rows_per = (N + 63) / 64;
  int r0 = chunk * rows_per;
  int r1 = min(N, r0 + rows_per);
  const unsigned short* base = emb + (size_t)t*N*256;
  int c0 = (tid & 31)*8, rg = tid >> 5;
  float s[8] = {0,0,0,0,0,0,0,0};
  for (int r = r0 + rg; r < r1; r += 8){
    uint4 v = *(const uint4*)(base + (size_t)r*256 + c0);
    s[0] += bf2f(v.x & 0xffffu); s[1] += bf2f(v.x >> 16);
    s[2] += bf2f(v.y & 0xffffu); s[3] += bf2f(v.y >> 16);
    s[4] += bf2f(v.z & 0xffffu); s[5] += bf2f(v.z >> 16);
    s[6] += bf2f(v.w & 0xffffu); s[7] += bf2f(v.w >> 16);
  }
  #pragma unroll
  for (int j=0;j<8;j++) red[rg][c0+j] = s[j];
  __syncthreads();
  float tot = 0.f;
  #pragma unroll
  for (int g=0;g<8;g++) tot += red[g][tid];
  atomicAdd(&sums[t*256 + tid], tot);
}

// ---------------- temporal attention weights (tiny) ----------------
__global__ __launch_bounds__(256) void k_attn(const float* __restrict__ sum_emb,
                                              const float* __restrict__ Wq, const float* __restrict__ bq,
                                              const float* __restrict__ Wk, const float* __restrict__ bk,
                                              float* __restrict__ aw, int N){
  __shared__ float mean_s[4][256];
  __shared__ float red[256];
  __shared__ float scores_s[4];
  int j = threadIdx.x;
  float invN = 1.0f/(float)N;
  #pragma unroll
  for (int t=0;t<4;t++) mean_s[t][j] = sum_emb[t*256+j]*invN;
  __syncthreads();
  float q3 = bq[j];
  float kt0=bk[j], kt1=bk[j], kt2=bk[j], kt3=bk[j];
  for (int m=0;m<256;m++){
    float wq = Wq[m*256+j];
    float wk = Wk[m*256+j];
    float m0 = mean_s[0][m], m1 = mean_s[1][m], m2 = mean_s[2][m], m3 = mean_s[3][m];
    q3  += m3*wq;
    kt0 += m0*wk; kt1 += m1*wk; kt2 += m2*wk; kt3 += m3*wk;
  }
  float kts0=kt0, kts1=kt1, kts2=kt2, kts3=kt3;
  #pragma unroll
  for (int t=0;t<4;t++){
    float ktv = (t==0)?kts0:((t==1)?kts1:((t==2)?kts2:kts3));
    red[j] = q3*ktv;
    __syncthreads();
    for (int off=128; off>0; off>>=1){
      if (j < off) red[j] += red[j+off];
      __syncthreads();
    }
    if (j==0) scores_s[t] = red[0]*(1.0f/16.0f);
    __syncthreads();
  }
  if (j==0){
    float mx = fmaxf(fmaxf(scores_s[0],scores_s[1]),fmaxf(scores_s[2],scores_s[3]));
    float w0 = __expf(scores_s[0]-mx), w1 = __expf(scores_s[1]-mx),
          w2 = __expf(scores_s[2]-mx), w3 = __expf(scores_s[3]-mx);
    float s = w0+w1+w2+w3;
    aw[0]=w0/s; aw[1]=w1/s; aw[2]=w2/s; aw[3]=w3/s;
  }
}

extern "C" void kernel_launch(void* const* d_in, const int* in_sizes, int n_in,
                              void* d_out, int out_size, void* d_ws, size_t ws_size,
                              hipStream_t stream){
  (void)n_in; (void)out_size; (void)ws_size;
  const float* x   = (const float*)d_in[0];
  const int*   ei  = (const int*)d_in[1];
  const float* Wp  = (const float*)d_in[2];
  const float* bp  = (const float*)d_in[3];
  const float* W0  = (const float*)d_in[4];
  const float* as0 = (const float*)d_in[5];
  const float* ad0 = (const float*)d_in[6];
  const float* b0  = (const float*)d_in[7];
  const float* W1  = (const float*)d_in[8];
  const float* as1 = (const float*)d_in[9];
  const float* ad1 = (const float*)d_in[10];
  const float* b1  = (const float*)d_in[11];
  const float* Wq  = (const float*)d_in[12];
  const float* bq  = (const float*)d_in[13];
  const float* Wk  = (const float*)d_in[14];
  const float* bk  = (const float*)d_in[15];
  const float* Wv  = (const float*)d_in[16];
  const float* bv  = (const float*)d_in[17];
  float* out = (float*)d_out;

  const int T = 4, FIN = 256;
  const int N = in_sizes[0] / (T*FIN);
  const int E = in_sizes[1] / 2;
  const int TN = T*N;
  const int* src = ei;
  const int* dst = ei + E;

  char* ws = (char*)d_ws;
  size_t cur = 0;
  auto alloc = [&](size_t bytes)->void*{
    void* p = ws + cur;
    cur += (bytes + 255) & ~(size_t)255;
    return p;
  };
  unsigned short* h0all = (unsigned short*)alloc((size_t)TN*64*2);
  unsigned short* bufA  = (unsigned short*)alloc((size_t)TN*256*2);   // agg0_all
  unsigned short* bufB  = (unsigned short*)alloc((size_t)TN*256*2);   // hp_all
  unsigned short* embs  = (unsigned short*)alloc((size_t)TN*256*2);
  float* e_s    = (float*)alloc((size_t)TN*4*4);
  float* e_d    = (float*)alloc((size_t)TN*4*4);
  float* sume   = (float*)alloc(4*256*4);
  float* aw     = (float*)alloc(256);
  float* ah0s   = (float*)alloc(256*4);
  float* ah0d   = (float*)alloc(256*4);
  int*   rowptr = (int*)alloc((size_t)(N+1)*4);
  int*   deg    = (int*)alloc((size_t)N*4);
  int*   pos    = (int*)alloc((size_t)N*4);
  int*   bsum   = (int*)alloc((size_t)256*4);
  int*   colidx = (int*)alloc((size_t)(E+N)*4);
  unsigned short* WpT  = (unsigned short*)alloc((size_t)64*256*2);
  unsigned short* W0T4 = (unsigned short*)alloc((size_t)4*64*64*2);
  unsigned short* W1T  = (unsigned short*)alloc((size_t)256*256*2);
  unsigned short* WvT  = (unsigned short*)alloc((size_t)256*256*2);

  int nb256 = (N+255)/256;
  int nbE   = (E+255)/256;
  int gmN   = (N+127)/128;
  int gagg  = (TN+3)/4;

  // weight prep + deg/sume zeroing (runs first; independent of CSR inputs)
  int prep_total = 165120 + N;
  k_prep<<<(prep_total+255)/256,256,0,stream>>>(Wp, W0, W1, Wv, as0, ad0,
                                                WpT, W0T4, W1T, WvT, ah0s, ah0d, deg, sume, N);

  // CSR build (graph static across t and layers)
  k_deg_count<<<nbE,256,0,stream>>>(dst, E, deg);
  k_scan_blk<<<nb256,256,0,stream>>>(deg, rowptr, bsum, N);
  k_scan_top<<<1,256,0,stream>>>(bsum, nb256, rowptr + N);
  k_scan_fix<<<nb256,256,0,stream>>>(rowptr, bsum, pos, colidx, N);
  k_fill_edges<<<nbE,256,0,stream>>>(src, dst, E, pos, colidx);

  // h0 for all 4 timesteps
  k_h0<<<(TN/64+3)/4 + 1,256,0,stream>>>(x, WpT, bp, h0all, TN, N);

  // GAT layer 0 (batched over t): logits, gather-agg, fused W0+W1 GEMM (+layer-1 logits)
  k_esd0<<<gagg,256,0,stream>>>(h0all, ah0s, ah0d, e_s, e_d, TN);
  k_agg0<<<dim3((N+3)/4, T),256,0,stream>>>(h0all, e_s, e_d, rowptr, colidx, bufA, N);
  k_gat01<<<(TN+63)/64,256,0,stream>>>(bufA, W0T4, b0, W1T, as1, ad1, bufB, e_s, e_d, TN);
  // GAT layer 1 aggregation (e_s/e_d already produced by k_gat01)
  k_agg<<<dim3((N+3)/4, T),256,0,stream>>>(bufB, e_s, e_d, rowptr, colidx, b1, embs, N);
  // node-mean numerators for temporal attention
  k_colsum<<<256,256,0,stream>>>(embs, sume, N);

  // temporal attention weights, then final GEMM with fused combine
  k_attn<<<1,256,0,stream>>>(sume, Wq, bq, Wk, bk, aw, N);
  k_gemm_fin<<<gmN,512,0,stream>>>(embs, aw, WvT, bv, out, N);
}